// Round 2
// baseline (1224.455 us; speedup 1.0000x reference)
//
#include <hip/hip_runtime.h>
#include <stdint.h>

#define DI __device__ __forceinline__

typedef __attribute__((ext_vector_type(8))) short bfx8;
typedef __attribute__((ext_vector_type(4))) short bfx4;
typedef __attribute__((ext_vector_type(4))) float f4;

DI unsigned short f2bf(float x){
  unsigned u = __float_as_uint(x);
  u = (u + 0x7FFFu + ((u >> 16) & 1u)) >> 16;
  return (unsigned short)u;
}
DI float bf2f(unsigned short h){ return __uint_as_float(((unsigned)h) << 16); }

DI f4 mfma32(bfx8 a, bfx8 b, f4 c){
  return __builtin_amdgcn_mfma_f32_16x16x32_bf16(a, b, c, 0, 0, 0);
}
#if __has_builtin(__builtin_amdgcn_mfma_f32_16x16x16bf16_1k)
DI f4 mfma16(bfx4 a, bfx4 b, f4 c){
  return __builtin_amdgcn_mfma_f32_16x16x16bf16_1k(a, b, c, 0, 0, 0);
}
#else
DI f4 mfma16(bfx4 a, bfx4 b, f4 c){
  f4 d = c;
  asm volatile("v_mfma_f32_16x16x16_bf16 %0, %1, %2, %0" : "+v"(d) : "v"(a), "v"(b));
  return d;
}
#endif

// ---------------- cast f32 -> bf16 (4-wide) ----------------
__global__ void k_cast(const float* __restrict__ src, unsigned short* __restrict__ dst, int n4){
  int i = blockIdx.x*256 + threadIdx.x;
  if (i < n4){
    const float4 v = ((const float4*)src)[i];
    bfx4 o;
    o[0] = (short)f2bf(v.x); o[1] = (short)f2bf(v.y);
    o[2] = (short)f2bf(v.z); o[3] = (short)f2bf(v.w);
    *(bfx4*)(dst + (size_t)i*4) = o;
  }
}

// relk_bf: [272][64] zero-padded rows; relvT_bf: [64][288] = rel_v^T zero-padded cols
__global__ void k_relprep(const float* __restrict__ rlk, const float* __restrict__ rlv,
                          unsigned short* __restrict__ relk_bf, unsigned short* __restrict__ relvT_bf){
  int i = blockIdx.x*256 + threadIdx.x;
  if (i < 272*64){
    int r = i >> 6, d = i & 63;
    relk_bf[i] = (r < 257) ? f2bf(rlk[r*64 + d]) : (unsigned short)0;
  }
  if (i < 64*288){
    int d = i / 288, r = i % 288;
    relvT_bf[i] = (r < 257) ? f2bf(rlv[(size_t)r*64 + d]) : (unsigned short)0;
  }
}

// ---------------- QK projection: D[sb'][n] = x @ w^T ; Q scaled by 1/8 ----------------
__global__ __launch_bounds__(256) void k_qk(
    const unsigned short* __restrict__ xbf, const unsigned short* __restrict__ wq,
    const unsigned short* __restrict__ wk, unsigned short* __restrict__ Qb,
    unsigned short* __restrict__ Kb)
{
  const int w = threadIdx.x >> 6, lane = threadIdx.x & 63;
  const int p = lane & 15, g = lane >> 4;
  const int r0 = blockIdx.x*64 + w*16;
  const int b = r0 >> 10, s0 = r0 & 1023;
  const int n0 = blockIdx.y*64;
  const bool isQ = (n0 < 1024);
  const unsigned short* wsel = isQ ? wq : wk;
  const int nn0 = n0 & 1023;
  const f4 fz = {0.f,0.f,0.f,0.f};
  f4 acc[4] = {fz,fz,fz,fz};
  const unsigned short* arow = xbf + ((size_t)((s0 + p)*4 + b))*1024;
  for (int k0=0; k0<1024; k0+=32){
    bfx8 a = *(const bfx8*)(arow + k0 + 8*g);
#pragma unroll
    for (int f=0; f<4; ++f){
      bfx8 bb = *(const bfx8*)(wsel + (size_t)(nn0 + 16*f + p)*1024 + k0 + 8*g);
      acc[f] = mfma32(a, bb, acc[f]);
    }
  }
  unsigned short* dst = isQ ? Qb : Kb;
  const float scl = isQ ? 0.125f : 1.0f;
#pragma unroll
  for (int f=0; f<4; ++f){
    int col = nn0 + 16*f + p;
    int h = col >> 6, d = col & 63;
#pragma unroll
    for (int r=0; r<4; ++r){
      int srow = s0 + 4*g + r;
      dst[((size_t)(b*16 + h)*1024 + srow)*64 + d] = f2bf(acc[f][r] * scl);
    }
  }
}

// ---------------- V projection transposed: VT layout [b][h][d][s] ----------------
__global__ __launch_bounds__(256) void k_v(
    const unsigned short* __restrict__ xbf, const unsigned short* __restrict__ wv,
    unsigned short* __restrict__ VT)
{
  const int w = threadIdx.x >> 6, lane = threadIdx.x & 63;
  const int p = lane & 15, g = lane >> 4;
  const int n0 = blockIdx.x*64 + w*16;
  const int c0 = blockIdx.y*64;
  const int b = c0 >> 10, s0 = c0 & 1023;
  const f4 fz = {0.f,0.f,0.f,0.f};
  f4 acc[4] = {fz,fz,fz,fz};
  const unsigned short* arow = wv + (size_t)(n0 + p)*1024;
  for (int k0=0; k0<1024; k0+=32){
    bfx8 a = *(const bfx8*)(arow + k0 + 8*g);
#pragma unroll
    for (int f=0; f<4; ++f){
      bfx8 bb = *(const bfx8*)(xbf + ((size_t)((s0 + 16*f + p)*4 + b))*1024 + k0 + 8*g);
      acc[f] = mfma32(a, bb, acc[f]);
    }
  }
#pragma unroll
  for (int f=0; f<4; ++f){
#pragma unroll
    for (int r=0; r<4; ++r){
      int n = n0 + 4*g + r; int h = n >> 6, d = n & 63;
      int srow = s0 + 16*f + p;
      VT[((size_t)(b*16 + h)*64 + d)*1024 + srow] = f2bf(acc[f][r]);
    }
  }
}

// ---------------- Qr[bh][s][272] = Qscaled @ rel_k^T (bf16) ----------------
__global__ __launch_bounds__(256) void k_qr(
    const unsigned short* __restrict__ Qb, const unsigned short* __restrict__ relk,
    unsigned short* __restrict__ Qr)
{
  const int bh = blockIdx.x;
  const int w = threadIdx.x >> 6, lane = threadIdx.x & 63;
  const int p = lane & 15, g = lane >> 4;
  const int s0 = blockIdx.y*64 + w*16;
  const f4 fz = {0.f,0.f,0.f,0.f};
  bfx8 a0 = *(const bfx8*)(Qb + ((size_t)bh*1024 + s0 + p)*64 + 8*g);
  bfx8 a1 = *(const bfx8*)(Qb + ((size_t)bh*1024 + s0 + p)*64 + 32 + 8*g);
  for (int r0=0; r0<272; r0+=16){
    f4 acc = fz;
    bfx8 b0 = *(const bfx8*)(relk + (size_t)(r0 + p)*64 + 8*g);
    bfx8 b1 = *(const bfx8*)(relk + (size_t)(r0 + p)*64 + 32 + 8*g);
    acc = mfma32(a0, b0, acc);
    acc = mfma32(a1, b1, acc);
#pragma unroll
    for (int r=0; r<4; ++r)
      Qr[((size_t)bh*1024 + s0 + 4*g + r)*272 + r0 + p] = f2bf(acc[r]);
  }
}

// ---------------- fused attention, t-split x4 ----------------
// block: (b, s-tile of 16) x t-quarter. 4 waves = 4 head-groups of 4 heads.
// scores TRANSPOSED: S^T = K @ Q^T. Softmax over heads WITHOUT max pass
// (scores ~ N(0,2), exp safe in fp32) -> 1 barrier per iteration.
// Each t-quarter writes its own bf16 partial output + tail buckets.
__global__ __launch_bounds__(256, 3) void k_attn(
    const unsigned short* __restrict__ Qb, const unsigned short* __restrict__ Kb,
    const unsigned short* __restrict__ VT, const unsigned short* __restrict__ Qr,
    unsigned short* __restrict__ attnS, float* __restrict__ tails,
    unsigned short* __restrict__ op0, unsigned short* __restrict__ op1,
    unsigned short* __restrict__ op2, unsigned short* __restrict__ op3)
{
  __shared__ __align__(16) float red[2][4][256];   // parity x wave x (64 lanes * f4)
  __shared__ __align__(16) float tbuf[4][16][68];  // per-wave transpose slab (staged epilogue)
  const int bid = blockIdx.x;
  const int tpart = blockIdx.y;
  const int tbase = tpart << 8;            // 256 t-values per part
  const int b = bid >> 6;
  const int s0 = (bid & 63) << 4;
  const int w = threadIdx.x >> 6;
  const int lane = threadIdx.x & 63;
  const int p = lane & 15, g = lane >> 4;
  const int s = s0 + p;
  const int h0 = w * 4;
  const f4 fz = {0.f,0.f,0.f,0.f};

  bfx8 qf[4][2];
#pragma unroll
  for (int hh=0; hh<4; ++hh){
    size_t base = ((size_t)(b*16 + h0 + hh) * 1024 + s) * 64;
#pragma unroll
    for (int kf=0; kf<2; ++kf)
      qf[hh][kf] = *(const bfx8*)(Qb + base + kf*32 + 8*g);
  }

  f4 o[4][4];
#pragma unroll
  for (int hh=0; hh<4; ++hh)
#pragma unroll
    for (int df=0; df<4; ++df) o[hh][df] = fz;

  float tl0[4] = {0.f,0.f,0.f,0.f};
  float tl1[4] = {0.f,0.f,0.f,0.f};

  bfx8 kc[4][2]; bfx4 vc[4][4]; unsigned short qc[4][4];
  bfx8 kn[4][2]; bfx4 vn[4][4]; unsigned short qn[4][4];

#pragma unroll
  for (int hh=0; hh<4; ++hh){
    size_t bh = (size_t)(b*16 + h0 + hh);
#pragma unroll
    for (int kf=0; kf<2; ++kf)
      kc[hh][kf] = *(const bfx8*)(Kb + (bh*1024 + tbase + p)*64 + kf*32 + 8*g);
#pragma unroll
    for (int df=0; df<4; ++df)
      vc[hh][df] = *(const bfx4*)(VT + (bh*64 + df*16 + p)*1024 + tbase + 4*g);
#pragma unroll
    for (int r=0; r<4; ++r){
      int t = tbase + 4*g + r;
      int u = s - t + 128; u = u < 0 ? 0 : (u > 256 ? 256 : u);
      qc[hh][r] = Qr[(bh*1024 + s)*272 + u];
    }
  }

  for (int it=0; it<16; ++it){
    const int t0 = tbase + (it << 4);
    const int buf = it & 1;

    f4 sc[4];
#pragma unroll
    for (int hh=0; hh<4; ++hh){
      f4 t = mfma32(kc[hh][0], qf[hh][0], fz);
      sc[hh] = mfma32(kc[hh][1], qf[hh][1], t);
    }

    if (it < 15){
      const int t1 = t0 + 16;
#pragma unroll
      for (int hh=0; hh<4; ++hh){
        size_t bh = (size_t)(b*16 + h0 + hh);
#pragma unroll
        for (int kf=0; kf<2; ++kf)
          kn[hh][kf] = *(const bfx8*)(Kb + (bh*1024 + t1 + p)*64 + kf*32 + 8*g);
#pragma unroll
        for (int df=0; df<4; ++df)
          vn[hh][df] = *(const bfx4*)(VT + (bh*64 + df*16 + p)*1024 + t1 + 4*g);
#pragma unroll
        for (int r=0; r<4; ++r){
          int t = t1 + 4*g + r;
          int u = s - t + 128; u = u < 0 ? 0 : (u > 256 ? 256 : u);
          qn[hh][r] = Qr[(bh*1024 + s)*272 + u];
        }
      }
    }

    // exp (no max subtraction) + partial sum over this wave's 4 heads
    f4 e[4]; f4 ps = fz;
#pragma unroll
    for (int hh=0; hh<4; ++hh)
#pragma unroll
      for (int r=0; r<4; ++r){
        float v = __expf(sc[hh][r] + bf2f(qc[hh][r]));
        e[hh][r] = v; ps[r] += v;
      }
    *(f4*)&red[buf][w][lane*4] = ps;
    __syncthreads();
    f4 S = *(const f4*)&red[buf][0][lane*4];
#pragma unroll
    for (int ww=1; ww<4; ++ww){
      f4 t = *(const f4*)&red[buf][ww][lane*4];
#pragma unroll
      for (int r=0; r<4; ++r) S[r] += t[r];
    }
    f4 inv;
#pragma unroll
    for (int r=0; r<4; ++r) inv[r] = 1.0f / S[r];

#pragma unroll
    for (int hh=0; hh<4; ++hh){
      size_t bh = (size_t)(b*16 + h0 + hh);
      f4 at;
#pragma unroll
      for (int r=0; r<4; ++r) at[r] = e[hh][r] * inv[r];
#pragma unroll
      for (int r=0; r<4; ++r){
        int t = t0 + 4*g + r;
        int u = s - t + 128;
        float a = at[r];
        if (u <= 0) tl0[hh] += a;
        else if (u >= 256) tl1[hh] += a;
        else attnS[(bh*1024 + s)*288 + u] = f2bf(a);
      }
      bfx4 pk;
#pragma unroll
      for (int r=0; r<4; ++r) pk[r] = (short)f2bf(at[r]);
#pragma unroll
      for (int df=0; df<4; ++df)
        o[hh][df] = mfma16(vc[hh][df], pk, o[hh][df]);
    }

    if (it < 15){
#pragma unroll
      for (int hh=0; hh<4; ++hh){
#pragma unroll
        for (int kf=0; kf<2; ++kf) kc[hh][kf] = kn[hh][kf];
#pragma unroll
        for (int df=0; df<4; ++df) vc[hh][df] = vn[hh][df];
#pragma unroll
        for (int r=0; r<4; ++r) qc[hh][r] = qn[hh][r];
      }
    }
  }

  // tail buckets for this t-part
#pragma unroll
  for (int hh=0; hh<4; ++hh){
    float v0 = tl0[hh];
    v0 += __shfl_xor(v0, 16, 64);
    v0 += __shfl_xor(v0, 32, 64);
    float v1 = tl1[hh];
    v1 += __shfl_xor(v1, 16, 64);
    v1 += __shfl_xor(v1, 32, 64);
    if (g == 0){
      size_t bh = (size_t)(b*16 + h0 + hh);
      tails[(((size_t)tpart << 16) + bh*1024 + s)*2 + 0] = v0;
      tails[(((size_t)tpart << 16) + bh*1024 + s)*2 + 1] = v1;
    }
  }

  // staged transpose epilogue -> bf16 partial output for this t-part
  unsigned short* dst = (tpart == 0) ? op0 : (tpart == 1) ? op1 : (tpart == 2) ? op2 : op3;
#pragma unroll
  for (int hh=0; hh<4; ++hh){
    float (*tb)[68] = tbuf[w];
#pragma unroll
    for (int df=0; df<4; ++df)
      *(f4*)&tb[p][df*16 + 4*g] = o[hh][df];
    __syncthreads();
    const int srow = lane >> 2, quad = lane & 3;
    f4 r0 = *(const f4*)&tb[srow][quad*16 + 0];
    f4 r1 = *(const f4*)&tb[srow][quad*16 + 4];
    f4 r2 = *(const f4*)&tb[srow][quad*16 + 8];
    f4 r3 = *(const f4*)&tb[srow][quad*16 + 12];
    bfx8 pa, pb;
#pragma unroll
    for (int j=0; j<4; ++j){
      pa[j]   = (short)f2bf(r0[j]);
      pa[j+4] = (short)f2bf(r1[j]);
      pb[j]   = (short)f2bf(r2[j]);
      pb[j+4] = (short)f2bf(r3[j]);
    }
    size_t addr = ((size_t)b*1024 + s0 + srow)*1024 + (h0+hh)*64 + quad*16;
    *(bfx8*)(dst + addr) = pa;
    *(bfx8*)(dst + addr + 8) = pb;
    __syncthreads();
  }
}

// ---------------- out2^T = rel_v^T @ attnS^T (+tails) + sum of 4 partials -> out1 ----------------
__global__ __launch_bounds__(256) void k_outrel(
    const unsigned short* __restrict__ attnS, const unsigned short* __restrict__ relvT,
    const float* __restrict__ tails, const float* __restrict__ relv,
    const unsigned short* __restrict__ op1, const unsigned short* __restrict__ op2,
    const unsigned short* __restrict__ op3, unsigned short* __restrict__ out1)
{
  __shared__ __align__(16) float tbuf[4][16][68];
  const int bh = blockIdx.x;
  const int w = threadIdx.x >> 6, lane = threadIdx.x & 63;
  const int p = lane & 15, g = lane >> 4;
  const int s0 = blockIdx.y*64 + w*16;
  const f4 fz = {0.f,0.f,0.f,0.f};
  f4 acc[4] = {fz,fz,fz,fz};
  const size_t arow = ((size_t)bh*1024 + s0 + p)*288;
#pragma unroll
  for (int kk=0; kk<288; kk+=32){
    bfx8 bb = *(const bfx8*)(attnS + arow + kk + 8*g);
#pragma unroll
    for (int df=0; df<4; ++df){
      bfx8 a = *(const bfx8*)(relvT + (size_t)(df*16 + p)*288 + kk + 8*g);
      acc[df] = mfma32(a, bb, acc[df]);
    }
  }
  float tv0 = 0.f, tv1 = 0.f;
#pragma unroll
  for (int tp=0; tp<4; ++tp){
    size_t tix = (((size_t)tp << 16) + (size_t)bh*1024 + s0 + p)*2;
    tv0 += tails[tix + 0];
    tv1 += tails[tix + 1];
  }
#pragma unroll
  for (int df=0; df<4; ++df)
#pragma unroll
    for (int r=0; r<4; ++r){
      int d = df*16 + 4*g + r;
      acc[df][r] += tv0 * relv[d] + tv1 * relv[256*64 + d];
    }
  float (*tb)[68] = tbuf[w];
#pragma unroll
  for (int df=0; df<4; ++df)
    *(f4*)&tb[p][df*16 + 4*g] = acc[df];
  __syncthreads();
  const int srow = lane >> 2, quad = lane & 3;
  f4 r0 = *(const f4*)&tb[srow][quad*16 + 0];
  f4 r1 = *(const f4*)&tb[srow][quad*16 + 4];
  f4 r2 = *(const f4*)&tb[srow][quad*16 + 8];
  f4 r3 = *(const f4*)&tb[srow][quad*16 + 12];
  size_t addr = ((size_t)(bh>>4)*1024 + s0 + srow)*1024 + (bh&15)*64 + quad*16;
  bfx8 o0 = *(bfx8*)(out1 + addr);
  bfx8 o1 = *(bfx8*)(out1 + addr + 8);
  bfx8 p1a = *(const bfx8*)(op1 + addr);
  bfx8 p1b = *(const bfx8*)(op1 + addr + 8);
  bfx8 p2a = *(const bfx8*)(op2 + addr);
  bfx8 p2b = *(const bfx8*)(op2 + addr + 8);
  bfx8 p3a = *(const bfx8*)(op3 + addr);
  bfx8 p3b = *(const bfx8*)(op3 + addr + 8);
  bfx8 n0v, n1v;
#pragma unroll
  for (int j=0; j<4; ++j){
    float a0 = bf2f((unsigned short)o0[j])   + bf2f((unsigned short)p1a[j])
             + bf2f((unsigned short)p2a[j])  + bf2f((unsigned short)p3a[j]) + r0[j];
    float a1 = bf2f((unsigned short)o0[j+4]) + bf2f((unsigned short)p1a[j+4])
             + bf2f((unsigned short)p2a[j+4])+ bf2f((unsigned short)p3a[j+4]) + r1[j];
    float a2 = bf2f((unsigned short)o1[j])   + bf2f((unsigned short)p1b[j])
             + bf2f((unsigned short)p2b[j])  + bf2f((unsigned short)p3b[j]) + r2[j];
    float a3 = bf2f((unsigned short)o1[j+4]) + bf2f((unsigned short)p1b[j+4])
             + bf2f((unsigned short)p2b[j+4])+ bf2f((unsigned short)p3b[j+4]) + r3[j];
    n0v[j]   = (short)f2bf(a0);
    n0v[j+4] = (short)f2bf(a1);
    n1v[j]   = (short)f2bf(a2);
    n1v[j+4] = (short)f2bf(a3);
  }
  *(bfx8*)(out1 + addr) = n0v;
  *(bfx8*)(out1 + addr + 8) = n1v;
}

// ---------------- final projection: d_out[(s,b)][n] = out1 @ w_o^T + b_o ----------------
__global__ __launch_bounds__(256) void k_wo(
    const unsigned short* __restrict__ out1, const unsigned short* __restrict__ wo,
    const float* __restrict__ bo, float* __restrict__ dout)
{
  const int bm = blockIdx.x;
  const int b = bm >> 4;
  const int w = threadIdx.x >> 6, lane = threadIdx.x & 63;
  const int p = lane & 15, g = lane >> 4;
  const int s0 = (bm & 15)*64 + w*16;
  const int n0 = blockIdx.y*64;
  const f4 fz = {0.f,0.f,0.f,0.f};
  f4 acc[4] = {fz,fz,fz,fz};
  const unsigned short* arow = out1 + ((size_t)b*1024 + s0 + p)*1024;
  for (int k0=0; k0<1024; k0+=32){
    bfx8 a = *(const bfx8*)(arow + k0 + 8*g);
#pragma unroll
    for (int f=0; f<4; ++f){
      bfx8 bb = *(const bfx8*)(wo + (size_t)(n0 + 16*f + p)*1024 + k0 + 8*g);
      acc[f] = mfma32(a, bb, acc[f]);
    }
  }
#pragma unroll
  for (int f=0; f<4; ++f){
    int col = n0 + 16*f + p;
    float bias = bo[col];
#pragma unroll
    for (int r=0; r<4; ++r){
      int srow = s0 + 4*g + r;
      dout[((size_t)srow*4 + b)*1024 + col] = acc[f][r] + bias;
    }
  }
}

extern "C" void kernel_launch(void* const* d_in, const int* in_sizes, int n_in,
                              void* d_out, int out_size, void* d_ws, size_t ws_size,
                              hipStream_t stream){
  const float* x   = (const float*)d_in[0];
  const float* wq  = (const float*)d_in[1];
  const float* wk  = (const float*)d_in[2];
  const float* wv  = (const float*)d_in[3];
  const float* wo  = (const float*)d_in[4];
  const float* bo  = (const float*)d_in[5];
  const float* rlk = (const float*)d_in[6];
  const float* rlv = (const float*)d_in[7];
  char* ws = (char*)d_ws;

  unsigned short* x_bf    = (unsigned short*)(ws + 0);          // 8 MB; reused as op1 after projections
  unsigned short* wq_bf   = (unsigned short*)(ws + 8388608);
  unsigned short* wk_bf   = (unsigned short*)(ws + 10485760);
  unsigned short* wv_bf   = (unsigned short*)(ws + 12582912);
  unsigned short* wo_bf   = (unsigned short*)(ws + 14680064);
  unsigned short* relk_bf = (unsigned short*)(ws + 16777216);
  unsigned short* relvT_bf= (unsigned short*)(ws + 16812032);
  unsigned short* Qb      = (unsigned short*)(ws + 16848896);
  unsigned short* Kb      = (unsigned short*)(ws + 25237504);
  unsigned short* VT      = (unsigned short*)(ws + 33626112);
  unsigned short* Qr      = (unsigned short*)(ws + 42014720);   // 35.65 MB, ends 77666304
  unsigned short* attnS   = (unsigned short*)(ws + 77666304);   // 37.75 MB, ends 115415040
  float*          tails   = (float*)        (ws + 115415040);   // 4 x 64 x 1024 x 2 f32 = 2 MB, ends 117512192
  unsigned short* out1    = (unsigned short*)(ws + 117512192);  // 8 MB (= op0), ends 125900800
  unsigned short* op2     = (unsigned short*)(ws + 125900800);  // 8 MB, ends 134289408
  unsigned short* op3     = (unsigned short*)(ws + 134289408);  // 8 MB, ends 142677952
  unsigned short* op1     = x_bf;                               // x_bf dead after k_qk/k_v

  k_cast<<<4096, 256, 0, stream>>>(x,  x_bf,  1048576);
  k_cast<<<1024, 256, 0, stream>>>(wq, wq_bf, 262144);
  k_cast<<<1024, 256, 0, stream>>>(wk, wk_bf, 262144);
  k_cast<<<1024, 256, 0, stream>>>(wv, wv_bf, 262144);
  k_cast<<<1024, 256, 0, stream>>>(wo, wo_bf, 262144);
  k_relprep<<<72, 256, 0, stream>>>(rlk, rlv, relk_bf, relvT_bf);

  k_qk<<<dim3(64,32), 256, 0, stream>>>(x_bf, wq_bf, wk_bf, Qb, Kb);
  k_v <<<dim3(16,64), 256, 0, stream>>>(x_bf, wv_bf, VT);
  k_qr<<<dim3(64,16), 256, 0, stream>>>(Qb, relk_bf, Qr);

  (void)hipMemsetAsync(attnS, 0, (size_t)37748736, stream);
  k_attn<<<dim3(256,4), 256, 0, stream>>>(Qb, Kb, VT, Qr, attnS, tails, out1, op1, op2, op3);
  k_outrel<<<dim3(64,16), 256, 0, stream>>>(attnS, relvT_bf, tails, rlv, op1, op2, op3, out1);
  k_wo<<<dim3(64,16), 256, 0, stream>>>(out1, wo_bf, bo, (float*)d_out);
}

// Round 3
// 641.608 us; speedup vs baseline: 1.9084x; 1.9084x over previous
//
#include <hip/hip_runtime.h>
#include <stdint.h>

#define DI __device__ __forceinline__

typedef __attribute__((ext_vector_type(8))) short bfx8;
typedef __attribute__((ext_vector_type(4))) short bfx4;
typedef __attribute__((ext_vector_type(4))) float f4;

DI unsigned short f2bf(float x){
  unsigned u = __float_as_uint(x);
  u = (u + 0x7FFFu + ((u >> 16) & 1u)) >> 16;
  return (unsigned short)u;
}
DI float bf2f(unsigned short h){ return __uint_as_float(((unsigned)h) << 16); }

DI f4 mfma32(bfx8 a, bfx8 b, f4 c){
  return __builtin_amdgcn_mfma_f32_16x16x32_bf16(a, b, c, 0, 0, 0);
}
#if __has_builtin(__builtin_amdgcn_mfma_f32_16x16x16bf16_1k)
DI f4 mfma16(bfx4 a, bfx4 b, f4 c){
  return __builtin_amdgcn_mfma_f32_16x16x16bf16_1k(a, b, c, 0, 0, 0);
}
#else
DI f4 mfma16(bfx4 a, bfx4 b, f4 c){
  f4 d = c;
  asm volatile("v_mfma_f32_16x16x16_bf16 %0, %1, %2, %0" : "+v"(d) : "v"(a), "v"(b));
  return d;
}
#endif

// ---------------- cast f32 -> bf16 (4-wide) ----------------
__global__ void k_cast(const float* __restrict__ src, unsigned short* __restrict__ dst, int n4){
  int i = blockIdx.x*256 + threadIdx.x;
  if (i < n4){
    const float4 v = ((const float4*)src)[i];
    bfx4 o;
    o[0] = (short)f2bf(v.x); o[1] = (short)f2bf(v.y);
    o[2] = (short)f2bf(v.z); o[3] = (short)f2bf(v.w);
    *(bfx4*)(dst + (size_t)i*4) = o;
  }
}

// relk_bf: [272][64] zero-padded rows; relvT_bf: [64][288] = rel_v^T zero-padded cols
__global__ void k_relprep(const float* __restrict__ rlk, const float* __restrict__ rlv,
                          unsigned short* __restrict__ relk_bf, unsigned short* __restrict__ relvT_bf){
  int i = blockIdx.x*256 + threadIdx.x;
  if (i < 272*64){
    int r = i >> 6, d = i & 63;
    relk_bf[i] = (r < 257) ? f2bf(rlk[r*64 + d]) : (unsigned short)0;
  }
  if (i < 64*288){
    int d = i / 288, r = i % 288;
    relvT_bf[i] = (r < 257) ? f2bf(rlv[(size_t)r*64 + d]) : (unsigned short)0;
  }
}

// ---------------- QK projection: D[sb'][n] = x @ w^T ; Q scaled by 1/8 ----------------
__global__ __launch_bounds__(256) void k_qk(
    const unsigned short* __restrict__ xbf, const unsigned short* __restrict__ wq,
    const unsigned short* __restrict__ wk, unsigned short* __restrict__ Qb,
    unsigned short* __restrict__ Kb)
{
  const int w = threadIdx.x >> 6, lane = threadIdx.x & 63;
  const int p = lane & 15, g = lane >> 4;
  const int r0 = blockIdx.x*64 + w*16;
  const int b = r0 >> 10, s0 = r0 & 1023;
  const int n0 = blockIdx.y*64;
  const bool isQ = (n0 < 1024);
  const unsigned short* wsel = isQ ? wq : wk;
  const int nn0 = n0 & 1023;
  const f4 fz = {0.f,0.f,0.f,0.f};
  f4 acc[4] = {fz,fz,fz,fz};
  const unsigned short* arow = xbf + ((size_t)((s0 + p)*4 + b))*1024;
  for (int k0=0; k0<1024; k0+=32){
    bfx8 a = *(const bfx8*)(arow + k0 + 8*g);
#pragma unroll
    for (int f=0; f<4; ++f){
      bfx8 bb = *(const bfx8*)(wsel + (size_t)(nn0 + 16*f + p)*1024 + k0 + 8*g);
      acc[f] = mfma32(a, bb, acc[f]);
    }
  }
  unsigned short* dst = isQ ? Qb : Kb;
  const float scl = isQ ? 0.125f : 1.0f;
#pragma unroll
  for (int f=0; f<4; ++f){
    int col = nn0 + 16*f + p;
    int h = col >> 6, d = col & 63;
#pragma unroll
    for (int r=0; r<4; ++r){
      int srow = s0 + 4*g + r;
      dst[((size_t)(b*16 + h)*1024 + srow)*64 + d] = f2bf(acc[f][r] * scl);
    }
  }
}

// ---------------- V projection transposed: VT layout [b][h][d][s] ----------------
__global__ __launch_bounds__(256) void k_v(
    const unsigned short* __restrict__ xbf, const unsigned short* __restrict__ wv,
    unsigned short* __restrict__ VT)
{
  const int w = threadIdx.x >> 6, lane = threadIdx.x & 63;
  const int p = lane & 15, g = lane >> 4;
  const int n0 = blockIdx.x*64 + w*16;
  const int c0 = blockIdx.y*64;
  const int b = c0 >> 10, s0 = c0 & 1023;
  const f4 fz = {0.f,0.f,0.f,0.f};
  f4 acc[4] = {fz,fz,fz,fz};
  const unsigned short* arow = wv + (size_t)(n0 + p)*1024;
  for (int k0=0; k0<1024; k0+=32){
    bfx8 a = *(const bfx8*)(arow + k0 + 8*g);
#pragma unroll
    for (int f=0; f<4; ++f){
      bfx8 bb = *(const bfx8*)(xbf + ((size_t)((s0 + 16*f + p)*4 + b))*1024 + k0 + 8*g);
      acc[f] = mfma32(a, bb, acc[f]);
    }
  }
#pragma unroll
  for (int f=0; f<4; ++f){
#pragma unroll
    for (int r=0; r<4; ++r){
      int n = n0 + 4*g + r; int h = n >> 6, d = n & 63;
      int srow = s0 + 16*f + p;
      VT[((size_t)(b*16 + h)*64 + d)*1024 + srow] = f2bf(acc[f][r]);
    }
  }
}

// ---------------- Qr[bh][s][272] = Qscaled @ rel_k^T (bf16) ----------------
__global__ __launch_bounds__(256) void k_qr(
    const unsigned short* __restrict__ Qb, const unsigned short* __restrict__ relk,
    unsigned short* __restrict__ Qr)
{
  const int bh = blockIdx.x;
  const int w = threadIdx.x >> 6, lane = threadIdx.x & 63;
  const int p = lane & 15, g = lane >> 4;
  const int s0 = blockIdx.y*64 + w*16;
  const f4 fz = {0.f,0.f,0.f,0.f};
  bfx8 a0 = *(const bfx8*)(Qb + ((size_t)bh*1024 + s0 + p)*64 + 8*g);
  bfx8 a1 = *(const bfx8*)(Qb + ((size_t)bh*1024 + s0 + p)*64 + 32 + 8*g);
  for (int r0=0; r0<272; r0+=16){
    f4 acc = fz;
    bfx8 b0 = *(const bfx8*)(relk + (size_t)(r0 + p)*64 + 8*g);
    bfx8 b1 = *(const bfx8*)(relk + (size_t)(r0 + p)*64 + 32 + 8*g);
    acc = mfma32(a0, b0, acc);
    acc = mfma32(a1, b1, acc);
#pragma unroll
    for (int r=0; r<4; ++r)
      Qr[((size_t)bh*1024 + s0 + 4*g + r)*272 + r0 + p] = f2bf(acc[r]);
  }
}

// ---------------- fused attention ----------------
// One block per (b, s-tile of 16); 8 waves x 2 heads. All t in-block (64 iters).
// Scores TRANSPOSED (S^T = K@Q^T); softmax over heads, max-free, 1 barrier/iter.
// Skewed rel-v matrix staged in LDS (scatter->LDS), coalesced global stores at end.
// XCD remap: pbid%8 = 2*b + (st&1)  => each XCD's L2 holds one batch's K+V (4MB).
__global__ __launch_bounds__(512, 2) void k_attn(
    const unsigned short* __restrict__ Qb, const unsigned short* __restrict__ Kb,
    const unsigned short* __restrict__ VT, const unsigned short* __restrict__ Qr,
    unsigned short* __restrict__ attnS, float* __restrict__ tails,
    unsigned short* __restrict__ out1)
{
  __shared__ __align__(16) unsigned short skew[256*260];  // 133,120 B; aliased as tbuf in epilogue B
  __shared__ __align__(16) float red[2][8][256];          // 16,384 B
  const int pbid = blockIdx.x;
  const int xcd = pbid & 7;
  const int b = xcd >> 1;
  const int st = ((pbid >> 3) << 1) | (xcd & 1);
  const int s0 = st << 4;
  const int w = threadIdx.x >> 6;
  const int lane = threadIdx.x & 63;
  const int p = lane & 15, g = lane >> 4;
  const int s = s0 + p;
  const int h0 = w * 2;
  const f4 fz = {0.f,0.f,0.f,0.f};

  // zero the skew stage
  for (int i = threadIdx.x; i < 256*260/2; i += 512)
    ((unsigned*)skew)[i] = 0u;

  bfx8 qf[2][2];
#pragma unroll
  for (int hh=0; hh<2; ++hh){
    size_t base = ((size_t)(b*16 + h0 + hh) * 1024 + s) * 64;
#pragma unroll
    for (int kf=0; kf<2; ++kf)
      qf[hh][kf] = *(const bfx8*)(Qb + base + kf*32 + 8*g);
  }

  f4 o[2][4];
#pragma unroll
  for (int hh=0; hh<2; ++hh)
#pragma unroll
    for (int df=0; df<4; ++df) o[hh][df] = fz;

  float tl0[2] = {0.f,0.f};
  float tl1[2] = {0.f,0.f};

  bfx8 kc[2][2]; bfx4 vc[2][4]; unsigned short qc[2][4];
  bfx8 kn[2][2]; bfx4 vn[2][4]; unsigned short qn[2][4];

#pragma unroll
  for (int hh=0; hh<2; ++hh){
    size_t bh = (size_t)(b*16 + h0 + hh);
#pragma unroll
    for (int kf=0; kf<2; ++kf)
      kc[hh][kf] = *(const bfx8*)(Kb + (bh*1024 + p)*64 + kf*32 + 8*g);
#pragma unroll
    for (int df=0; df<4; ++df)
      vc[hh][df] = *(const bfx4*)(VT + (bh*64 + df*16 + p)*1024 + 4*g);
#pragma unroll
    for (int r=0; r<4; ++r){
      int t = 4*g + r;
      int u = s - t + 128; u = u < 0 ? 0 : (u > 256 ? 256 : u);
      qc[hh][r] = Qr[(bh*1024 + s)*272 + u];
    }
  }

  __syncthreads();  // skew zero-init complete

  for (int it=0; it<64; ++it){
    const int t0 = it << 4;
    const int buf = it & 1;

    f4 sc[2];
#pragma unroll
    for (int hh=0; hh<2; ++hh){
      f4 t = mfma32(kc[hh][0], qf[hh][0], fz);
      sc[hh] = mfma32(kc[hh][1], qf[hh][1], t);
    }

    if (it < 63){
      const int t1 = t0 + 16;
#pragma unroll
      for (int hh=0; hh<2; ++hh){
        size_t bh = (size_t)(b*16 + h0 + hh);
#pragma unroll
        for (int kf=0; kf<2; ++kf)
          kn[hh][kf] = *(const bfx8*)(Kb + (bh*1024 + t1 + p)*64 + kf*32 + 8*g);
#pragma unroll
        for (int df=0; df<4; ++df)
          vn[hh][df] = *(const bfx4*)(VT + (bh*64 + df*16 + p)*1024 + t1 + 4*g);
#pragma unroll
        for (int r=0; r<4; ++r){
          int t = t1 + 4*g + r;
          int u = s - t + 128; u = u < 0 ? 0 : (u > 256 ? 256 : u);
          qn[hh][r] = Qr[(bh*1024 + s)*272 + u];
        }
      }
    }

    // exp (max-free) + partial sum over this wave's 2 heads
    f4 e[2]; f4 ps = fz;
#pragma unroll
    for (int hh=0; hh<2; ++hh)
#pragma unroll
      for (int r=0; r<4; ++r){
        float v = __expf(sc[hh][r] + bf2f(qc[hh][r]));
        e[hh][r] = v; ps[r] += v;
      }
    *(f4*)&red[buf][w][lane*4] = ps;
    __syncthreads();
    f4 S = *(const f4*)&red[buf][0][lane*4];
#pragma unroll
    for (int ww=1; ww<8; ++ww){
      f4 t = *(const f4*)&red[buf][ww][lane*4];
#pragma unroll
      for (int r=0; r<4; ++r) S[r] += t[r];
    }
    f4 inv;
#pragma unroll
    for (int r=0; r<4; ++r) inv[r] = 1.0f / S[r];

#pragma unroll
    for (int hh=0; hh<2; ++hh){
      f4 at;
#pragma unroll
      for (int r=0; r<4; ++r) at[r] = e[hh][r] * inv[r];
      const int row = (h0 + hh)*16 + p;
#pragma unroll
      for (int r=0; r<4; ++r){
        int t = t0 + 4*g + r;
        int u = s - t + 128;
        float a = at[r];
        if (u <= 0) tl0[hh] += a;
        else if (u >= 256) tl1[hh] += a;
        else skew[row*260 + u] = f2bf(a);
      }
      bfx4 pk;
#pragma unroll
      for (int r=0; r<4; ++r) pk[r] = (short)f2bf(at[r]);
#pragma unroll
      for (int df=0; df<4; ++df)
        o[hh][df] = mfma16(vc[hh][df], pk, o[hh][df]);
    }

    if (it < 63){
#pragma unroll
      for (int hh=0; hh<2; ++hh){
#pragma unroll
        for (int kf=0; kf<2; ++kf) kc[hh][kf] = kn[hh][kf];
#pragma unroll
        for (int df=0; df<4; ++df) vc[hh][df] = vn[hh][df];
#pragma unroll
        for (int r=0; r<4; ++r) qc[hh][r] = qn[hh][r];
      }
    }
  }

  // tail buckets
#pragma unroll
  for (int hh=0; hh<2; ++hh){
    float v0 = tl0[hh];
    v0 += __shfl_xor(v0, 16, 64);
    v0 += __shfl_xor(v0, 32, 64);
    float v1 = tl1[hh];
    v1 += __shfl_xor(v1, 16, 64);
    v1 += __shfl_xor(v1, 32, 64);
    if (g == 0){
      size_t bh = (size_t)(b*16 + h0 + hh);
      tails[(bh*1024 + s)*2 + 0] = v0;
      tails[(bh*1024 + s)*2 + 1] = v1;
    }
  }

  __syncthreads();  // all skew ds_writes complete

  // Epilogue A: coalesced attnS row stores. 8 waves x 32 rows; 64 lanes x 4 bf16 = u 0..255.
  // (u=256..287 stays memset-zero; u=0 and u=256 are zero by construction.)
#pragma unroll 4
  for (int j=0; j<32; ++j){
    int ri = w*32 + j;
    int h = ri >> 4, pr = ri & 15;
    size_t bh = (size_t)(b*16 + h);
    bfx4 v = *(const bfx4*)(&skew[ri*260 + lane*4]);
    *(bfx4*)(attnS + (bh*1024 + s0 + pr)*288 + lane*4) = v;
  }

  __syncthreads();  // all skew reads complete before aliasing as tbuf

  // Epilogue B: transpose O^T frags -> out1[b][s][h*64+d], reusing skew LDS as per-wave slabs
  float* slab = (float*)skew + w*(16*68);  // 4352 B per wave
#pragma unroll
  for (int hh=0; hh<2; ++hh){
    float (*tb)[68] = (float(*)[68])slab;
#pragma unroll
    for (int df=0; df<4; ++df)
      *(f4*)&tb[p][df*16 + 4*g] = o[hh][df];
    __syncthreads();
    const int srow = lane >> 2, quad = lane & 3;
    f4 r0 = *(const f4*)&tb[srow][quad*16 + 0];
    f4 r1 = *(const f4*)&tb[srow][quad*16 + 4];
    f4 r2 = *(const f4*)&tb[srow][quad*16 + 8];
    f4 r3 = *(const f4*)&tb[srow][quad*16 + 12];
    bfx8 pa, pb;
#pragma unroll
    for (int j=0; j<4; ++j){
      pa[j]   = (short)f2bf(r0[j]);
      pa[j+4] = (short)f2bf(r1[j]);
      pb[j]   = (short)f2bf(r2[j]);
      pb[j+4] = (short)f2bf(r3[j]);
    }
    size_t addr = ((size_t)b*1024 + s0 + srow)*1024 + (h0+hh)*64 + quad*16;
    *(bfx8*)(out1 + addr) = pa;
    *(bfx8*)(out1 + addr + 8) = pb;
    __syncthreads();
  }
}

// ---------------- out2^T = rel_v^T @ attnS^T (+ tails), RMW into out1 ----------------
__global__ __launch_bounds__(256) void k_outrel(
    const unsigned short* __restrict__ attnS, const unsigned short* __restrict__ relvT,
    const float* __restrict__ tails, const float* __restrict__ relv,
    unsigned short* __restrict__ out1)
{
  __shared__ __align__(16) float tbuf[4][16][68];
  const int bh = blockIdx.x;
  const int w = threadIdx.x >> 6, lane = threadIdx.x & 63;
  const int p = lane & 15, g = lane >> 4;
  const int s0 = blockIdx.y*64 + w*16;
  const f4 fz = {0.f,0.f,0.f,0.f};
  f4 acc[4] = {fz,fz,fz,fz};
  const size_t arow = ((size_t)bh*1024 + s0 + p)*288;
#pragma unroll
  for (int kk=0; kk<288; kk+=32){
    bfx8 bb = *(const bfx8*)(attnS + arow + kk + 8*g);
#pragma unroll
    for (int df=0; df<4; ++df){
      bfx8 a = *(const bfx8*)(relvT + (size_t)(df*16 + p)*288 + kk + 8*g);
      acc[df] = mfma32(a, bb, acc[df]);
    }
  }
  float tv0 = tails[((size_t)bh*1024 + s0 + p)*2 + 0];
  float tv1 = tails[((size_t)bh*1024 + s0 + p)*2 + 1];
#pragma unroll
  for (int df=0; df<4; ++df)
#pragma unroll
    for (int r=0; r<4; ++r){
      int d = df*16 + 4*g + r;
      acc[df][r] += tv0 * relv[d] + tv1 * relv[256*64 + d];
    }
  float (*tb)[68] = tbuf[w];
#pragma unroll
  for (int df=0; df<4; ++df)
    *(f4*)&tb[p][df*16 + 4*g] = acc[df];
  __syncthreads();
  const int srow = lane >> 2, quad = lane & 3;
  f4 r0 = *(const f4*)&tb[srow][quad*16 + 0];
  f4 r1 = *(const f4*)&tb[srow][quad*16 + 4];
  f4 r2 = *(const f4*)&tb[srow][quad*16 + 8];
  f4 r3 = *(const f4*)&tb[srow][quad*16 + 12];
  size_t addr = ((size_t)(bh>>4)*1024 + s0 + srow)*1024 + (bh&15)*64 + quad*16;
  bfx8 o0 = *(bfx8*)(out1 + addr);
  bfx8 o1 = *(bfx8*)(out1 + addr + 8);
  bfx8 n0v, n1v;
#pragma unroll
  for (int j=0; j<4; ++j){
    n0v[j]   = (short)f2bf(bf2f((unsigned short)o0[j])   + r0[j]);
    n0v[j+4] = (short)f2bf(bf2f((unsigned short)o0[j+4]) + r1[j]);
    n1v[j]   = (short)f2bf(bf2f((unsigned short)o1[j])   + r2[j]);
    n1v[j+4] = (short)f2bf(bf2f((unsigned short)o1[j+4]) + r3[j]);
  }
  *(bfx8*)(out1 + addr) = n0v;
  *(bfx8*)(out1 + addr + 8) = n1v;
}

// ---------------- final projection: d_out[(s,b)][n] = out1 @ w_o^T + b_o ----------------
__global__ __launch_bounds__(256) void k_wo(
    const unsigned short* __restrict__ out1, const unsigned short* __restrict__ wo,
    const float* __restrict__ bo, float* __restrict__ dout)
{
  const int bm = blockIdx.x;
  const int b = bm >> 4;
  const int w = threadIdx.x >> 6, lane = threadIdx.x & 63;
  const int p = lane & 15, g = lane >> 4;
  const int s0 = (bm & 15)*64 + w*16;
  const int n0 = blockIdx.y*64;
  const f4 fz = {0.f,0.f,0.f,0.f};
  f4 acc[4] = {fz,fz,fz,fz};
  const unsigned short* arow = out1 + ((size_t)b*1024 + s0 + p)*1024;
  for (int k0=0; k0<1024; k0+=32){
    bfx8 a = *(const bfx8*)(arow + k0 + 8*g);
#pragma unroll
    for (int f=0; f<4; ++f){
      bfx8 bb = *(const bfx8*)(wo + (size_t)(n0 + 16*f + p)*1024 + k0 + 8*g);
      acc[f] = mfma32(a, bb, acc[f]);
    }
  }
#pragma unroll
  for (int f=0; f<4; ++f){
    int col = n0 + 16*f + p;
    float bias = bo[col];
#pragma unroll
    for (int r=0; r<4; ++r){
      int srow = s0 + 4*g + r;
      dout[((size_t)srow*4 + b)*1024 + col] = acc[f][r] + bias;
    }
  }
}

extern "C" void kernel_launch(void* const* d_in, const int* in_sizes, int n_in,
                              void* d_out, int out_size, void* d_ws, size_t ws_size,
                              hipStream_t stream){
  const float* x   = (const float*)d_in[0];
  const float* wq  = (const float*)d_in[1];
  const float* wk  = (const float*)d_in[2];
  const float* wv  = (const float*)d_in[3];
  const float* wo  = (const float*)d_in[4];
  const float* bo  = (const float*)d_in[5];
  const float* rlk = (const float*)d_in[6];
  const float* rlv = (const float*)d_in[7];
  char* ws = (char*)d_ws;

  unsigned short* x_bf    = (unsigned short*)(ws + 0);
  unsigned short* wq_bf   = (unsigned short*)(ws + 8388608);
  unsigned short* wk_bf   = (unsigned short*)(ws + 10485760);
  unsigned short* wv_bf   = (unsigned short*)(ws + 12582912);
  unsigned short* wo_bf   = (unsigned short*)(ws + 14680064);
  unsigned short* relk_bf = (unsigned short*)(ws + 16777216);
  unsigned short* relvT_bf= (unsigned short*)(ws + 16812032);
  unsigned short* Qb      = (unsigned short*)(ws + 16848896);
  unsigned short* Kb      = (unsigned short*)(ws + 25237504);
  unsigned short* VT      = (unsigned short*)(ws + 33626112);
  unsigned short* Qr      = (unsigned short*)(ws + 42014720);   // 35.65 MB
  unsigned short* attnS   = (unsigned short*)(ws + 77666304);   // 37.75 MB
  float*          tails   = (float*)        (ws + 115415040);   // 512 KB
  unsigned short* out1    = (unsigned short*)(ws + 115939328);  // 8 MB
  // total ws use: 124,327,936 bytes

  k_cast<<<4096, 256, 0, stream>>>(x,  x_bf,  1048576);
  k_cast<<<1024, 256, 0, stream>>>(wq, wq_bf, 262144);
  k_cast<<<1024, 256, 0, stream>>>(wk, wk_bf, 262144);
  k_cast<<<1024, 256, 0, stream>>>(wv, wv_bf, 262144);
  k_cast<<<1024, 256, 0, stream>>>(wo, wo_bf, 262144);
  k_relprep<<<72, 256, 0, stream>>>(rlk, rlv, relk_bf, relvT_bf);

  k_qk<<<dim3(64,32), 256, 0, stream>>>(x_bf, wq_bf, wk_bf, Qb, Kb);
  k_v <<<dim3(16,64), 256, 0, stream>>>(x_bf, wv_bf, VT);
  k_qr<<<dim3(64,16), 256, 0, stream>>>(Qb, relk_bf, Qr);

  (void)hipMemsetAsync(attnS, 0, (size_t)37748736, stream);
  k_attn<<<256, 512, 0, stream>>>(Qb, Kb, VT, Qr, attnS, tails, out1);
  k_outrel<<<dim3(64,16), 256, 0, stream>>>(attnS, relvT_bf, tails, rlv, out1);
  k_wo<<<dim3(64,16), 256, 0, stream>>>(out1, wo_bf, bo, (float*)d_out);
}

// Round 4
// 605.071 us; speedup vs baseline: 2.0237x; 1.0604x over previous
//
#include <hip/hip_runtime.h>
#include <stdint.h>

#define DI __device__ __forceinline__

typedef __attribute__((ext_vector_type(8))) short bfx8;
typedef __attribute__((ext_vector_type(4))) short bfx4;
typedef __attribute__((ext_vector_type(4))) float f4;

DI unsigned short f2bf(float x){
  unsigned u = __float_as_uint(x);
  u = (u + 0x7FFFu + ((u >> 16) & 1u)) >> 16;
  return (unsigned short)u;
}
DI float bf2f(unsigned short h){ return __uint_as_float(((unsigned)h) << 16); }

DI f4 mfma32(bfx8 a, bfx8 b, f4 c){
  return __builtin_amdgcn_mfma_f32_16x16x32_bf16(a, b, c, 0, 0, 0);
}
#if __has_builtin(__builtin_amdgcn_mfma_f32_16x16x16bf16_1k)
DI f4 mfma16(bfx4 a, bfx4 b, f4 c){
  return __builtin_amdgcn_mfma_f32_16x16x16bf16_1k(a, b, c, 0, 0, 0);
}
#else
DI f4 mfma16(bfx4 a, bfx4 b, f4 c){
  f4 d = c;
  asm volatile("v_mfma_f32_16x16x16_bf16 %0, %1, %2, %0" : "+v"(d) : "v"(a), "v"(b));
  return d;
}
#endif

// ---------------- cast f32 -> bf16 (4-wide) ----------------
__global__ void k_cast(const float* __restrict__ src, unsigned short* __restrict__ dst, int n4){
  int i = blockIdx.x*256 + threadIdx.x;
  if (i < n4){
    const float4 v = ((const float4*)src)[i];
    bfx4 o;
    o[0] = (short)f2bf(v.x); o[1] = (short)f2bf(v.y);
    o[2] = (short)f2bf(v.z); o[3] = (short)f2bf(v.w);
    *(bfx4*)(dst + (size_t)i*4) = o;
  }
}

// relk_bf: [272][64] zero-padded rows; relvT_bf: [64][288] = rel_v^T zero-padded cols
__global__ void k_relprep(const float* __restrict__ rlk, const float* __restrict__ rlv,
                          unsigned short* __restrict__ relk_bf, unsigned short* __restrict__ relvT_bf){
  int i = blockIdx.x*256 + threadIdx.x;
  if (i < 272*64){
    int r = i >> 6, d = i & 63;
    relk_bf[i] = (r < 257) ? f2bf(rlk[r*64 + d]) : (unsigned short)0;
  }
  if (i < 64*288){
    int d = i / 288, r = i % 288;
    relvT_bf[i] = (r < 257) ? f2bf(rlv[(size_t)r*64 + d]) : (unsigned short)0;
  }
}

// ---------------- QK projection: D[sb'][n] = x @ w^T ; Q scaled by 1/8 ----------------
__global__ __launch_bounds__(256) void k_qk(
    const unsigned short* __restrict__ xbf, const unsigned short* __restrict__ wq,
    const unsigned short* __restrict__ wk, unsigned short* __restrict__ Qb,
    unsigned short* __restrict__ Kb)
{
  const int w = threadIdx.x >> 6, lane = threadIdx.x & 63;
  const int p = lane & 15, g = lane >> 4;
  const int r0 = blockIdx.x*64 + w*16;
  const int b = r0 >> 10, s0 = r0 & 1023;
  const int n0 = blockIdx.y*64;
  const bool isQ = (n0 < 1024);
  const unsigned short* wsel = isQ ? wq : wk;
  const int nn0 = n0 & 1023;
  const f4 fz = {0.f,0.f,0.f,0.f};
  f4 acc[4] = {fz,fz,fz,fz};
  const unsigned short* arow = xbf + ((size_t)((s0 + p)*4 + b))*1024;
  for (int k0=0; k0<1024; k0+=32){
    bfx8 a = *(const bfx8*)(arow + k0 + 8*g);
#pragma unroll
    for (int f=0; f<4; ++f){
      bfx8 bb = *(const bfx8*)(wsel + (size_t)(nn0 + 16*f + p)*1024 + k0 + 8*g);
      acc[f] = mfma32(a, bb, acc[f]);
    }
  }
  unsigned short* dst = isQ ? Qb : Kb;
  const float scl = isQ ? 0.125f : 1.0f;
#pragma unroll
  for (int f=0; f<4; ++f){
    int col = nn0 + 16*f + p;
    int h = col >> 6, d = col & 63;
#pragma unroll
    for (int r=0; r<4; ++r){
      int srow = s0 + 4*g + r;
      dst[((size_t)(b*16 + h)*1024 + srow)*64 + d] = f2bf(acc[f][r] * scl);
    }
  }
}

// ---------------- V projection transposed: VT layout [b][h][d][s] ----------------
__global__ __launch_bounds__(256) void k_v(
    const unsigned short* __restrict__ xbf, const unsigned short* __restrict__ wv,
    unsigned short* __restrict__ VT)
{
  const int w = threadIdx.x >> 6, lane = threadIdx.x & 63;
  const int p = lane & 15, g = lane >> 4;
  const int n0 = blockIdx.x*64 + w*16;
  const int c0 = blockIdx.y*64;
  const int b = c0 >> 10, s0 = c0 & 1023;
  const f4 fz = {0.f,0.f,0.f,0.f};
  f4 acc[4] = {fz,fz,fz,fz};
  const unsigned short* arow = wv + (size_t)(n0 + p)*1024;
  for (int k0=0; k0<1024; k0+=32){
    bfx8 a = *(const bfx8*)(arow + k0 + 8*g);
#pragma unroll
    for (int f=0; f<4; ++f){
      bfx8 bb = *(const bfx8*)(xbf + ((size_t)((s0 + 16*f + p)*4 + b))*1024 + k0 + 8*g);
      acc[f] = mfma32(a, bb, acc[f]);
    }
  }
#pragma unroll
  for (int f=0; f<4; ++f){
#pragma unroll
    for (int r=0; r<4; ++r){
      int n = n0 + 4*g + r; int h = n >> 6, d = n & 63;
      int srow = s0 + 16*f + p;
      VT[((size_t)(b*16 + h)*64 + d)*1024 + srow] = f2bf(acc[f][r]);
    }
  }
}

// ---------------- Qr[bh][s][272] = Qscaled @ rel_k^T (bf16) ----------------
__global__ __launch_bounds__(256) void k_qr(
    const unsigned short* __restrict__ Qb, const unsigned short* __restrict__ relk,
    unsigned short* __restrict__ Qr)
{
  const int bh = blockIdx.x;
  const int w = threadIdx.x >> 6, lane = threadIdx.x & 63;
  const int p = lane & 15, g = lane >> 4;
  const int s0 = blockIdx.y*64 + w*16;
  const f4 fz = {0.f,0.f,0.f,0.f};
  bfx8 a0 = *(const bfx8*)(Qb + ((size_t)bh*1024 + s0 + p)*64 + 8*g);
  bfx8 a1 = *(const bfx8*)(Qb + ((size_t)bh*1024 + s0 + p)*64 + 32 + 8*g);
  for (int r0=0; r0<272; r0+=16){
    f4 acc = fz;
    bfx8 b0 = *(const bfx8*)(relk + (size_t)(r0 + p)*64 + 8*g);
    bfx8 b1 = *(const bfx8*)(relk + (size_t)(r0 + p)*64 + 32 + 8*g);
    acc = mfma32(a0, b0, acc);
    acc = mfma32(a1, b1, acc);
#pragma unroll
    for (int r=0; r<4; ++r)
      Qr[((size_t)bh*1024 + s0 + 4*g + r)*272 + r0 + p] = f2bf(acc[r]);
  }
}

// ---------------- far attention: tiles with |t - s| > window; u uniformly clipped ----------------
// grid: 1024 = (st<<4)|((part&1)<<3)|(b<<1)|(part>>1); XCD = low 3 bits => per-XCD (b, t-half) locality.
// No skew buffer, no Qr gather (u const 0 or 256). Writes partial O (bf16) + tail buckets per part.
__global__ __launch_bounds__(512, 3) void k_far(
    const unsigned short* __restrict__ Qb, const unsigned short* __restrict__ Kb,
    const unsigned short* __restrict__ VT, const unsigned short* __restrict__ Qr,
    float* __restrict__ tails, unsigned short* __restrict__ op)
{
  __shared__ __align__(16) float shmem[8][16][68];   // 34,816 B; first 16 KB doubles as red
  float (*red)[8][256] = reinterpret_cast<float(*)[8][256]>(&shmem[0][0][0]);

  const int pbid = blockIdx.x;
  const int b    = (pbid >> 1) & 3;
  const int part = ((pbid & 1) << 1) | ((pbid >> 3) & 1);
  const int st   = pbid >> 4;
  const int s0   = st << 4;
  const int w = threadIdx.x >> 6, lane = threadIdx.x & 63;
  const int p = lane & 15, g = lane >> 4;
  const int s = s0 + p;
  const int h0 = w * 2;
  const f4 fz = {0.f,0.f,0.f,0.f};

  bfx8 qf[2][2]; float qr0[2], qr1[2];
#pragma unroll
  for (int hh=0; hh<2; ++hh){
    size_t bh = (size_t)(b*16 + h0 + hh);
    size_t base = (bh*1024 + s)*64;
    qf[hh][0] = *(const bfx8*)(Qb + base + 8*g);
    qf[hh][1] = *(const bfx8*)(Qb + base + 32 + 8*g);
    qr0[hh] = bf2f(Qr[(bh*1024 + s)*272 + 0]);
    qr1[hh] = bf2f(Qr[(bh*1024 + s)*272 + 256]);
  }

  f4 o[2][4];
#pragma unroll
  for (int hh=0; hh<2; ++hh)
#pragma unroll
    for (int df=0; df<4; ++df) o[hh][df] = fz;
  float tl0[2] = {0.f,0.f};
  float tl1[2] = {0.f,0.f};
  int itp = 0;

  for (int ti = part*16; ti < part*16 + 16; ++ti){
    if (ti >= st-8 && ti <= st+8) continue;   // near tiles handled by k_near (block-uniform)
    const int t0 = ti << 4;
    const int buf = itp & 1; ++itp;
    const bool hi = (ti < st);                // true: u>=256 (tl1 side), else u<=0 (tl0 side)

    f4 sc[2]; bfx4 vc[2][4];
#pragma unroll
    for (int hh=0; hh<2; ++hh){
      size_t bh = (size_t)(b*16 + h0 + hh);
      bfx8 k0v = *(const bfx8*)(Kb + (bh*1024 + t0 + p)*64 + 8*g);
      bfx8 k1v = *(const bfx8*)(Kb + (bh*1024 + t0 + p)*64 + 32 + 8*g);
#pragma unroll
      for (int df=0; df<4; ++df)
        vc[hh][df] = *(const bfx4*)(VT + (bh*64 + df*16 + p)*1024 + t0 + 4*g);
      sc[hh] = mfma32(k1v, qf[hh][1], mfma32(k0v, qf[hh][0], fz));
    }

    f4 e[2]; f4 ps = fz;
#pragma unroll
    for (int hh=0; hh<2; ++hh){
      float qa = hi ? qr1[hh] : qr0[hh];
#pragma unroll
      for (int r=0; r<4; ++r){ float v = __expf(sc[hh][r] + qa); e[hh][r] = v; ps[r] += v; }
    }
    *(f4*)&red[buf][w][lane*4] = ps;
    __syncthreads();
    f4 S = *(const f4*)&red[buf][0][lane*4];
#pragma unroll
    for (int ww=1; ww<8; ++ww){
      f4 t = *(const f4*)&red[buf][ww][lane*4];
#pragma unroll
      for (int r=0; r<4; ++r) S[r] += t[r];
    }
    f4 inv;
#pragma unroll
    for (int r=0; r<4; ++r) inv[r] = 1.0f / S[r];

#pragma unroll
    for (int hh=0; hh<2; ++hh){
      f4 at;
#pragma unroll
      for (int r=0; r<4; ++r) at[r] = e[hh][r] * inv[r];
      float tsum = at[0] + at[1] + at[2] + at[3];
      if (hi) tl1[hh] += tsum; else tl0[hh] += tsum;
      bfx4 pk;
#pragma unroll
      for (int r=0; r<4; ++r) pk[r] = (short)f2bf(at[r]);
#pragma unroll
      for (int df=0; df<4; ++df)
        o[hh][df] = mfma16(vc[hh][df], pk, o[hh][df]);
    }
  }

  // tail buckets for this part
#pragma unroll
  for (int hh=0; hh<2; ++hh){
    float v0 = tl0[hh];
    v0 += __shfl_xor(v0, 16, 64);
    v0 += __shfl_xor(v0, 32, 64);
    float v1 = tl1[hh];
    v1 += __shfl_xor(v1, 16, 64);
    v1 += __shfl_xor(v1, 32, 64);
    if (g == 0){
      size_t tix = ((size_t)(part*64 + b*16 + h0 + hh)*1024 + s)*2;
      tails[tix + 0] = v0;
      tails[tix + 1] = v1;
    }
  }

  __syncthreads();   // red dead; reuse shmem as transpose slabs

  unsigned short* dst = op + (size_t)part * 4194304;
#pragma unroll
  for (int hh=0; hh<2; ++hh){
    float (*tb)[68] = shmem[w];
#pragma unroll
    for (int df=0; df<4; ++df)
      *(f4*)&tb[p][df*16 + 4*g] = o[hh][df];
    __syncthreads();
    const int srow = lane >> 2, quad = lane & 3;
    f4 r0 = *(const f4*)&tb[srow][quad*16 + 0];
    f4 r1 = *(const f4*)&tb[srow][quad*16 + 4];
    f4 r2 = *(const f4*)&tb[srow][quad*16 + 8];
    f4 r3 = *(const f4*)&tb[srow][quad*16 + 12];
    bfx8 pa, pb;
#pragma unroll
    for (int j=0; j<4; ++j){
      pa[j]   = (short)f2bf(r0[j]);
      pa[j+4] = (short)f2bf(r1[j]);
      pb[j]   = (short)f2bf(r2[j]);
      pb[j+4] = (short)f2bf(r3[j]);
    }
    size_t addr = ((size_t)b*1024 + s0 + srow)*1024 + (h0+hh)*64 + quad*16;
    *(bfx8*)(dst + addr) = pa;
    *(bfx8*)(dst + addr + 8) = pb;
    __syncthreads();
  }
}

// ---------------- near attention (17 tiles) + fused rel_v GEMM + final out1 ----------------
// One block per (b, s-tile); 8 waves x 2 heads. Skew scatter -> LDS; then out2 = rel_v^T @ skew
// straight from LDS; adds near+far tails and the 4 far partial outputs; writes out1.
__global__ __launch_bounds__(512, 2) void k_near(
    const unsigned short* __restrict__ Qb, const unsigned short* __restrict__ Kb,
    const unsigned short* __restrict__ VT, const unsigned short* __restrict__ Qr,
    const unsigned short* __restrict__ relvT, const float* __restrict__ relv,
    const float* __restrict__ tails, const unsigned short* __restrict__ op,
    unsigned short* __restrict__ out1)
{
  __shared__ __align__(16) unsigned short skew[256*272];  // 139,264 B; aliased as slabs at the end
  __shared__ __align__(16) float red[2][8][256];          // 16,384 B
  const int pbid = blockIdx.x;
  const int xcd = pbid & 7;
  const int b = xcd >> 1;
  const int st = ((pbid >> 3) << 1) | (xcd & 1);
  const int s0 = st << 4;
  const int w = threadIdx.x >> 6;
  const int lane = threadIdx.x & 63;
  const int p = lane & 15, g = lane >> 4;
  const int s = s0 + p;
  const int h0 = w * 2;
  const f4 fz = {0.f,0.f,0.f,0.f};

  for (int i = threadIdx.x; i < 256*272/2; i += 512)
    ((unsigned*)skew)[i] = 0u;

  bfx8 qf[2][2];
#pragma unroll
  for (int hh=0; hh<2; ++hh){
    size_t base = ((size_t)(b*16 + h0 + hh) * 1024 + s) * 64;
#pragma unroll
    for (int kf=0; kf<2; ++kf)
      qf[hh][kf] = *(const bfx8*)(Qb + base + kf*32 + 8*g);
  }

  f4 o[2][4];
#pragma unroll
  for (int hh=0; hh<2; ++hh)
#pragma unroll
    for (int df=0; df<4; ++df) o[hh][df] = fz;

  float tl0[2] = {0.f,0.f};
  float tl1[2] = {0.f,0.f};

  const int tlo = (st-8 < 0) ? 0 : st-8;
  const int thi = (st+8 > 63) ? 63 : st+8;
  const int tbase = tlo << 4;

  bfx8 kc[2][2]; bfx4 vc[2][4]; unsigned short qc[2][4];
  bfx8 kn[2][2]; bfx4 vn[2][4]; unsigned short qn[2][4];

#pragma unroll
  for (int hh=0; hh<2; ++hh){
    size_t bh = (size_t)(b*16 + h0 + hh);
#pragma unroll
    for (int kf=0; kf<2; ++kf)
      kc[hh][kf] = *(const bfx8*)(Kb + (bh*1024 + tbase + p)*64 + kf*32 + 8*g);
#pragma unroll
    for (int df=0; df<4; ++df)
      vc[hh][df] = *(const bfx4*)(VT + (bh*64 + df*16 + p)*1024 + tbase + 4*g);
#pragma unroll
    for (int r=0; r<4; ++r){
      int t = tbase + 4*g + r;
      int u = s - t + 128; u = u < 0 ? 0 : (u > 256 ? 256 : u);
      qc[hh][r] = Qr[(bh*1024 + s)*272 + u];
    }
  }

  __syncthreads();  // skew zero-init complete

  int itp = 0;
  for (int ti = tlo; ti <= thi; ++ti, ++itp){
    const int t0 = ti << 4;
    const int buf = itp & 1;

    f4 sc[2];
#pragma unroll
    for (int hh=0; hh<2; ++hh){
      f4 t = mfma32(kc[hh][0], qf[hh][0], fz);
      sc[hh] = mfma32(kc[hh][1], qf[hh][1], t);
    }

    if (ti < thi){
      const int t1 = t0 + 16;
#pragma unroll
      for (int hh=0; hh<2; ++hh){
        size_t bh = (size_t)(b*16 + h0 + hh);
#pragma unroll
        for (int kf=0; kf<2; ++kf)
          kn[hh][kf] = *(const bfx8*)(Kb + (bh*1024 + t1 + p)*64 + kf*32 + 8*g);
#pragma unroll
        for (int df=0; df<4; ++df)
          vn[hh][df] = *(const bfx4*)(VT + (bh*64 + df*16 + p)*1024 + t1 + 4*g);
#pragma unroll
        for (int r=0; r<4; ++r){
          int t = t1 + 4*g + r;
          int u = s - t + 128; u = u < 0 ? 0 : (u > 256 ? 256 : u);
          qn[hh][r] = Qr[(bh*1024 + s)*272 + u];
        }
      }
    }

    f4 e[2]; f4 ps = fz;
#pragma unroll
    for (int hh=0; hh<2; ++hh)
#pragma unroll
      for (int r=0; r<4; ++r){
        float v = __expf(sc[hh][r] + bf2f(qc[hh][r]));
        e[hh][r] = v; ps[r] += v;
      }
    *(f4*)&red[buf][w][lane*4] = ps;
    __syncthreads();
    f4 S = *(const f4*)&red[buf][0][lane*4];
#pragma unroll
    for (int ww=1; ww<8; ++ww){
      f4 t = *(const f4*)&red[buf][ww][lane*4];
#pragma unroll
      for (int r=0; r<4; ++r) S[r] += t[r];
    }
    f4 inv;
#pragma unroll
    for (int r=0; r<4; ++r) inv[r] = 1.0f / S[r];

#pragma unroll
    for (int hh=0; hh<2; ++hh){
      f4 at;
#pragma unroll
      for (int r=0; r<4; ++r) at[r] = e[hh][r] * inv[r];
      const int row = (h0 + hh)*16 + p;
#pragma unroll
      for (int r=0; r<4; ++r){
        int t = t0 + 4*g + r;
        int u = s - t + 128;
        float a = at[r];
        if (u <= 0) tl0[hh] += a;
        else if (u >= 256) tl1[hh] += a;
        else skew[row*272 + u] = f2bf(a);
      }
      bfx4 pk;
#pragma unroll
      for (int r=0; r<4; ++r) pk[r] = (short)f2bf(at[r]);
#pragma unroll
      for (int df=0; df<4; ++df)
        o[hh][df] = mfma16(vc[hh][df], pk, o[hh][df]);
    }

    if (ti < thi){
#pragma unroll
      for (int hh=0; hh<2; ++hh){
#pragma unroll
        for (int kf=0; kf<2; ++kf) kc[hh][kf] = kn[hh][kf];
#pragma unroll
        for (int df=0; df<4; ++df) vc[hh][df] = vn[hh][df];
#pragma unroll
        for (int r=0; r<4; ++r) qc[hh][r] = qn[hh][r];
      }
    }
  }

  __syncthreads();  // all skew scatter writes complete

  // ---- fused out2 = rel_v^T @ skew (u in [0,256), cols >=256 are zero) ----
  f4 acc2[2][4];
#pragma unroll
  for (int hh=0; hh<2; ++hh)
#pragma unroll
    for (int df=0; df<4; ++df) acc2[hh][df] = fz;
#pragma unroll
  for (int k0=0; k0<256; k0+=32){
    bfx8 bb0 = *(const bfx8*)&skew[(h0*16 + p)*272 + k0 + 8*g];
    bfx8 bb1 = *(const bfx8*)&skew[((h0+1)*16 + p)*272 + k0 + 8*g];
#pragma unroll
    for (int df=0; df<4; ++df){
      bfx8 a = *(const bfx8*)(relvT + (size_t)(df*16 + p)*288 + k0 + 8*g);
      acc2[0][df] = mfma32(a, bb0, acc2[0][df]);
      acc2[1][df] = mfma32(a, bb1, acc2[1][df]);
    }
  }

  // ---- tails (near in-register + 4 far parts) x rel_v rows 0 / 256 ----
  f4 rv0[4], rv1[4];
#pragma unroll
  for (int df=0; df<4; ++df){
    rv0[df] = *(const f4*)(relv + df*16 + 4*g);
    rv1[df] = *(const f4*)(relv + 16384 + df*16 + 4*g);
  }
#pragma unroll
  for (int hh=0; hh<2; ++hh){
    float tv0 = tl0[hh];
    tv0 += __shfl_xor(tv0, 16, 64);
    tv0 += __shfl_xor(tv0, 32, 64);
    float tv1 = tl1[hh];
    tv1 += __shfl_xor(tv1, 16, 64);
    tv1 += __shfl_xor(tv1, 32, 64);
    size_t bh = (size_t)(b*16 + h0 + hh);
#pragma unroll
    for (int part=0; part<4; ++part){
      size_t tix = ((size_t)(part*64) + bh)*2048 + (size_t)s*2;
      tv0 += tails[tix + 0];
      tv1 += tails[tix + 1];
    }
#pragma unroll
    for (int df=0; df<4; ++df)
#pragma unroll
      for (int r=0; r<4; ++r)
        o[hh][df][r] += acc2[hh][df][r] + tv0*rv0[df][r] + tv1*rv1[df][r];
  }

  __syncthreads();  // skew GEMM reads complete; alias as transpose slabs

  float* slabBase = (float*)skew;
  float (*tb)[68] = (float(*)[68])(slabBase + w*(16*68));
#pragma unroll
  for (int hh=0; hh<2; ++hh){
#pragma unroll
    for (int df=0; df<4; ++df)
      *(f4*)&tb[p][df*16 + 4*g] = o[hh][df];
    __syncthreads();
    const int srow = lane >> 2, quad = lane & 3;
    f4 r0 = *(const f4*)&tb[srow][quad*16 + 0];
    f4 r1 = *(const f4*)&tb[srow][quad*16 + 4];
    f4 r2 = *(const f4*)&tb[srow][quad*16 + 8];
    f4 r3 = *(const f4*)&tb[srow][quad*16 + 12];
    size_t addr = ((size_t)b*1024 + s0 + srow)*1024 + (h0+hh)*64 + quad*16;
    bfx8 pa, pb;
#pragma unroll
    for (int j=0; j<4; ++j){
      float a0 = r0[j], a1 = r1[j], a2 = r2[j], a3 = r3[j];
#pragma unroll
      for (int part=0; part<4; ++part){
        const unsigned short* pp = op + (size_t)part*4194304 + addr;
        bfx8 q0 = *(const bfx8*)pp;
        bfx8 q1 = *(const bfx8*)(pp + 8);
        a0 += bf2f((unsigned short)q0[j]);
        a1 += bf2f((unsigned short)q0[j+4]);
        a2 += bf2f((unsigned short)q1[j]);
        a3 += bf2f((unsigned short)q1[j+4]);
      }
      pa[j]   = (short)f2bf(a0);
      pa[j+4] = (short)f2bf(a1);
      pb[j]   = (short)f2bf(a2);
      pb[j+4] = (short)f2bf(a3);
    }
    *(bfx8*)(out1 + addr) = pa;
    *(bfx8*)(out1 + addr + 8) = pb;
    __syncthreads();
  }
}

// ---------------- final projection: d_out[(s,b)][n] = out1 @ w_o^T + b_o ----------------
__global__ __launch_bounds__(256) void k_wo(
    const unsigned short* __restrict__ out1, const unsigned short* __restrict__ wo,
    const float* __restrict__ bo, float* __restrict__ dout)
{
  const int bm = blockIdx.x;
  const int b = bm >> 4;
  const int w = threadIdx.x >> 6, lane = threadIdx.x & 63;
  const int p = lane & 15, g = lane >> 4;
  const int s0 = (bm & 15)*64 + w*16;
  const int n0 = blockIdx.y*64;
  const f4 fz = {0.f,0.f,0.f,0.f};
  f4 acc[4] = {fz,fz,fz,fz};
  const unsigned short* arow = out1 + ((size_t)b*1024 + s0 + p)*1024;
  for (int k0=0; k0<1024; k0+=32){
    bfx8 a = *(const bfx8*)(arow + k0 + 8*g);
#pragma unroll
    for (int f=0; f<4; ++f){
      bfx8 bb = *(const bfx8*)(wo + (size_t)(n0 + 16*f + p)*1024 + k0 + 8*g);
      acc[f] = mfma32(a, bb, acc[f]);
    }
  }
#pragma unroll
  for (int f=0; f<4; ++f){
    int col = n0 + 16*f + p;
    float bias = bo[col];
#pragma unroll
    for (int r=0; r<4; ++r){
      int srow = s0 + 4*g + r;
      dout[((size_t)srow*4 + b)*1024 + col] = acc[f][r] + bias;
    }
  }
}

extern "C" void kernel_launch(void* const* d_in, const int* in_sizes, int n_in,
                              void* d_out, int out_size, void* d_ws, size_t ws_size,
                              hipStream_t stream){
  const float* x   = (const float*)d_in[0];
  const float* wq  = (const float*)d_in[1];
  const float* wk  = (const float*)d_in[2];
  const float* wv  = (const float*)d_in[3];
  const float* wo  = (const float*)d_in[4];
  const float* bo  = (const float*)d_in[5];
  const float* rlk = (const float*)d_in[6];
  const float* rlv = (const float*)d_in[7];
  char* ws = (char*)d_ws;

  unsigned short* x_bf    = (unsigned short*)(ws + 0);
  unsigned short* wq_bf   = (unsigned short*)(ws + 8388608);
  unsigned short* wk_bf   = (unsigned short*)(ws + 10485760);
  unsigned short* wv_bf   = (unsigned short*)(ws + 12582912);
  unsigned short* wo_bf   = (unsigned short*)(ws + 14680064);
  unsigned short* relk_bf = (unsigned short*)(ws + 16777216);
  unsigned short* relvT_bf= (unsigned short*)(ws + 16812032);
  unsigned short* Qb      = (unsigned short*)(ws + 16848896);
  unsigned short* Kb      = (unsigned short*)(ws + 25237504);
  unsigned short* VT      = (unsigned short*)(ws + 33626112);
  unsigned short* Qr      = (unsigned short*)(ws + 42014720);   // 35.65 MB -> 77666304
  float*          tails   = (float*)        (ws + 77666304);   // 2 MB -> 79763456
  unsigned short* op      = (unsigned short*)(ws + 79763456);   // 32 MB (4 parts) -> 113317888
  unsigned short* out1    = (unsigned short*)(ws + 113317888);  // 8 MB -> 121706496

  k_cast<<<4096, 256, 0, stream>>>(x,  x_bf,  1048576);
  k_cast<<<1024, 256, 0, stream>>>(wq, wq_bf, 262144);
  k_cast<<<1024, 256, 0, stream>>>(wk, wk_bf, 262144);
  k_cast<<<1024, 256, 0, stream>>>(wv, wv_bf, 262144);
  k_cast<<<1024, 256, 0, stream>>>(wo, wo_bf, 262144);
  k_relprep<<<72, 256, 0, stream>>>(rlk, rlv, relk_bf, relvT_bf);

  k_qk<<<dim3(64,32), 256, 0, stream>>>(x_bf, wq_bf, wk_bf, Qb, Kb);
  k_v <<<dim3(16,64), 256, 0, stream>>>(x_bf, wv_bf, VT);
  k_qr<<<dim3(64,16), 256, 0, stream>>>(Qb, relk_bf, Qr);

  k_far <<<1024, 512, 0, stream>>>(Qb, Kb, VT, Qr, tails, op);
  k_near<<<256, 512, 0, stream>>>(Qb, Kb, VT, Qr, relvT_bf, rlv, tails, op, out1);
  k_wo<<<dim3(64,16), 256, 0, stream>>>(out1, wo_bf, bo, (float*)d_out);
}